// Round 1
// baseline (893.737 us; speedup 1.0000x reference)
//
#include <hip/hip_runtime.h>

// GIN: h1 = relu((scatter_add(x) + (1+eps0)*x) @ W0^T)
//      h2 = relu((scatter_add(h1) + (1+eps1)*h1) @ W1^T)
//      out = (h1 @ Wm^T + h2) / 2

// ---------------------------------------------------------------- init: agg = (1+eps)*h
__global__ __launch_bounds__(256) void init_scale_kernel(
    const float* __restrict__ h, const float* __restrict__ eps,
    float* __restrict__ agg, int total4)
{
    float s = 1.0f + eps[0];
    int i = blockIdx.x * blockDim.x + threadIdx.x;
    int stride = gridDim.x * blockDim.x;
    const float4* h4 = (const float4*)h;
    float4* a4 = (float4*)agg;
    for (; i < total4; i += stride) {
        float4 v = h4[i];
        v.x *= s; v.y *= s; v.z *= s; v.w *= s;
        a4[i] = v;
    }
}

// ---------------------------------------------------------------- scatter: agg[dst] += h[src]
// One edge per 64 lanes (one row of 64 floats), 4 edges per 256-thread block.
__global__ __launch_bounds__(256) void scatter_kernel(
    const float* __restrict__ h, const int* __restrict__ src,
    const int* __restrict__ dst, float* __restrict__ agg, int E)
{
    int lane = threadIdx.x & 63;
    int e = blockIdx.x * 4 + (threadIdx.x >> 6);
    if (e >= E) return;
    int s = src[e];
    int d = dst[e];
    float v = h[(size_t)s * 64 + lane];
    atomicAdd(&agg[(size_t)d * 64 + lane], v);
}

// ---------------------------------------------------------------- out = relu(A @ W^T)
// A: [n,64], W: [64,64] torch Linear layout (out,in). out[i][d] = sum_k A[i][k]*W[d][k].
// Block: 256 threads = 16 rows x (16 threads x 4 cols). W staged transposed in LDS.
__global__ __launch_bounds__(256) void gemm_relu_kernel(
    const float* __restrict__ A, const float* __restrict__ W,
    float* __restrict__ out, int n)
{
    __shared__ float Wt[64][64];   // Wt[k][d] = W[d][k]
    __shared__ float As[16][68];   // padded rows
    int tid = threadIdx.x;
    for (int i = tid; i < 4096; i += 256) {
        Wt[i & 63][i >> 6] = W[i];
    }
    int row0 = blockIdx.x * 16;
    {
        int r = tid >> 4;
        int c = (tid & 15) * 4;
        if (row0 + r < n) {
            float4 v = *(const float4*)&A[(size_t)(row0 + r) * 64 + c];
            As[r][c] = v.x; As[r][c + 1] = v.y; As[r][c + 2] = v.z; As[r][c + 3] = v.w;
        }
    }
    __syncthreads();
    int ty = tid >> 4;       // row within block
    int tx = tid & 15;       // col group (4 cols)
    if (row0 + ty >= n) return;
    float4 acc = make_float4(0.f, 0.f, 0.f, 0.f);
#pragma unroll
    for (int k = 0; k < 64; ++k) {
        float a = As[ty][k];
        float4 w = *(const float4*)&Wt[k][tx * 4];
        acc.x += a * w.x; acc.y += a * w.y; acc.z += a * w.z; acc.w += a * w.w;
    }
    acc.x = fmaxf(acc.x, 0.f); acc.y = fmaxf(acc.y, 0.f);
    acc.z = fmaxf(acc.z, 0.f); acc.w = fmaxf(acc.w, 0.f);
    *(float4*)&out[(size_t)(row0 + ty) * 64 + tx * 4] = acc;
}

// ---------------------------------------------------------------- out = (H1 @ Wm^T + relu(Agg @ W1^T)) / 2
// H1 may alias out: all reads of a block's rows are staged into LDS before writes.
__global__ __launch_bounds__(256) void final_kernel(
    const float* __restrict__ Agg, const float* __restrict__ H1,
    const float* __restrict__ W1, const float* __restrict__ Wm,
    float* __restrict__ out, int n)
{
    __shared__ float W1t[64][64];
    __shared__ float Wmt[64][64];
    __shared__ float As[16][68];
    __shared__ float Hs[16][68];
    int tid = threadIdx.x;
    for (int i = tid; i < 4096; i += 256) {
        W1t[i & 63][i >> 6] = W1[i];
        Wmt[i & 63][i >> 6] = Wm[i];
    }
    int row0 = blockIdx.x * 16;
    {
        int r = tid >> 4;
        int c = (tid & 15) * 4;
        if (row0 + r < n) {
            float4 v = *(const float4*)&Agg[(size_t)(row0 + r) * 64 + c];
            As[r][c] = v.x; As[r][c + 1] = v.y; As[r][c + 2] = v.z; As[r][c + 3] = v.w;
            float4 u = *(const float4*)&H1[(size_t)(row0 + r) * 64 + c];
            Hs[r][c] = u.x; Hs[r][c + 1] = u.y; Hs[r][c + 2] = u.z; Hs[r][c + 3] = u.w;
        }
    }
    __syncthreads();
    int ty = tid >> 4;
    int tx = tid & 15;
    if (row0 + ty >= n) return;
    float4 acc1 = make_float4(0.f, 0.f, 0.f, 0.f);  // Agg @ W1^T
    float4 acc2 = make_float4(0.f, 0.f, 0.f, 0.f);  // H1 @ Wm^T
#pragma unroll
    for (int k = 0; k < 64; ++k) {
        float a = As[ty][k];
        float hv = Hs[ty][k];
        float4 w1 = *(const float4*)&W1t[k][tx * 4];
        float4 wm = *(const float4*)&Wmt[k][tx * 4];
        acc1.x += a * w1.x; acc1.y += a * w1.y; acc1.z += a * w1.z; acc1.w += a * w1.w;
        acc2.x += hv * wm.x; acc2.y += hv * wm.y; acc2.z += hv * wm.z; acc2.w += hv * wm.w;
    }
    float4 r;
    r.x = (fmaxf(acc1.x, 0.f) + acc2.x) * 0.5f;
    r.y = (fmaxf(acc1.y, 0.f) + acc2.y) * 0.5f;
    r.z = (fmaxf(acc1.z, 0.f) + acc2.z) * 0.5f;
    r.w = (fmaxf(acc1.w, 0.f) + acc2.w) * 0.5f;
    *(float4*)&out[(size_t)(row0 + ty) * 64 + tx * 4] = r;
}

extern "C" void kernel_launch(void* const* d_in, const int* in_sizes, int n_in,
                              void* d_out, int out_size, void* d_ws, size_t ws_size,
                              hipStream_t stream)
{
    const float* x    = (const float*)d_in[0];
    const int*   ei   = (const int*)d_in[1];
    const float* W0   = (const float*)d_in[2];
    const float* eps0 = (const float*)d_in[3];
    const float* W1   = (const float*)d_in[4];
    const float* eps1 = (const float*)d_in[5];
    const float* Wm   = (const float*)d_in[6];
    float* out = (float*)d_out;

    int n = in_sizes[0] / 64;   // 100000
    int E = in_sizes[1] / 2;    // 1600000
    const int* src = ei;        // edge_index[0]
    const int* dst = ei + E;    // edge_index[1]

    float* agg = (float*)d_ws;  // n*64 floats = 25.6 MB scratch
    float* h1  = out;           // reuse d_out for h1 (final kernel is row-local safe)

    int total4 = n * 16;        // n*64/4
    int scatterBlocks = (E + 3) / 4;
    int gemmBlocks = (n + 15) / 16;

    // Layer 1
    init_scale_kernel<<<2048, 256, 0, stream>>>(x, eps0, agg, total4);
    scatter_kernel<<<scatterBlocks, 256, 0, stream>>>(x, src, dst, agg, E);
    gemm_relu_kernel<<<gemmBlocks, 256, 0, stream>>>(agg, W0, h1, n);

    // Layer 2 aggregation
    init_scale_kernel<<<2048, 256, 0, stream>>>(h1, eps1, agg, total4);
    scatter_kernel<<<scatterBlocks, 256, 0, stream>>>(h1, src, dst, agg, E);

    // Fused: out = (h1 @ Wm^T + relu(agg @ W1^T)) / 2
    final_kernel<<<gemmBlocks, 256, 0, stream>>>(agg, h1, W1, Wm, out, n);
}

// Round 2
// 632.777 us; speedup vs baseline: 1.4124x; 1.4124x over previous
//
#include <hip/hip_runtime.h>

// GIN: h1 = relu((scatter_add(x) + (1+eps0)*x) @ W0^T)
//      h2 = relu((scatter_add(h1) + (1+eps1)*h1) @ W1^T)
//      out = (h1 @ Wm^T + h2) / 2
//
// R2 strategy: build CSR-by-dst once per call (int atomics only), then
// gather-aggregate (one wave per node, lane=channel) fused with the 64x64
// GEMM (+relu). No fp32 atomics anywhere. Fallback to R1 atomic-scatter
// path if ws_size can't hold h1 + CSR (~33.2 MB).

// ================================================================ CSR build
__global__ __launch_bounds__(256) void zero_int_kernel(int* __restrict__ p, int n)
{
    int i = blockIdx.x * blockDim.x + threadIdx.x;
    int stride = gridDim.x * blockDim.x;
    for (; i < n; i += stride) p[i] = 0;
}

__global__ __launch_bounds__(256) void hist_kernel(
    const int* __restrict__ dst, int* __restrict__ deg, int E)
{
    int e = blockIdx.x * blockDim.x + threadIdx.x;
    if (e < E) atomicAdd(&deg[dst[e]], 1);
}

// scanA: per-block exclusive scan of 1024 elements (256 thr x 4), write block total
__global__ __launch_bounds__(256) void scanA_kernel(
    const int* __restrict__ deg, int* __restrict__ off,
    int* __restrict__ bsum, int n)
{
    __shared__ int tmp[256];
    int t = threadIdx.x;
    int base = blockIdx.x * 1024 + t * 4;
    int v0 = 0, v1 = 0, v2 = 0, v3 = 0;
    if (base + 3 < n) {
        int4 q = *(const int4*)&deg[base];
        v0 = q.x; v1 = q.y; v2 = q.z; v3 = q.w;
    } else {
        if (base + 0 < n) v0 = deg[base + 0];
        if (base + 1 < n) v1 = deg[base + 1];
        if (base + 2 < n) v2 = deg[base + 2];
    }
    int tot = v0 + v1 + v2 + v3;
    tmp[t] = tot;
    __syncthreads();
    for (int d = 1; d < 256; d <<= 1) {
        int x = (t >= d) ? tmp[t - d] : 0;
        __syncthreads();
        tmp[t] += x;
        __syncthreads();
    }
    int incl = tmp[t];
    int p = incl - tot;  // exclusive prefix within block
    if (base + 0 < n) off[base + 0] = p;
    if (base + 1 < n) off[base + 1] = p + v0;
    if (base + 2 < n) off[base + 2] = p + v0 + v1;
    if (base + 3 < n) off[base + 3] = p + v0 + v1 + v2;
    if (t == 255) bsum[blockIdx.x] = incl;  // block total
}

// scanB: exclusive scan of up to 256 block sums (single block)
__global__ __launch_bounds__(256) void scanB_kernel(int* __restrict__ bsum, int nb)
{
    __shared__ int tmp[256];
    int t = threadIdx.x;
    int v = (t < nb) ? bsum[t] : 0;
    tmp[t] = v;
    __syncthreads();
    for (int d = 1; d < 256; d <<= 1) {
        int x = (t >= d) ? tmp[t - d] : 0;
        __syncthreads();
        tmp[t] += x;
        __syncthreads();
    }
    if (t < nb) bsum[t] = tmp[t] - v;
}

// scanC: add block offsets, copy to cursor, write off[n]=E
__global__ __launch_bounds__(256) void scanC_kernel(
    int* __restrict__ off, int* __restrict__ cursor,
    const int* __restrict__ bsum, int n, int E)
{
    int t = threadIdx.x;
    int add = bsum[blockIdx.x];
    int base = blockIdx.x * 1024 + t * 4;
#pragma unroll
    for (int q = 0; q < 4; ++q) {
        int idx = base + q;
        if (idx < n) {
            int v = off[idx] + add;
            off[idx] = v;
            cursor[idx] = v;
        }
    }
    if (blockIdx.x == 0 && t == 0) off[n] = E;
}

__global__ __launch_bounds__(256) void fill_kernel(
    const int* __restrict__ src, const int* __restrict__ dst,
    int* __restrict__ cursor, int* __restrict__ bucket, int E)
{
    int e = blockIdx.x * blockDim.x + threadIdx.x;
    if (e < E) {
        int d = dst[e];
        int p = atomicAdd(&cursor[d], 1);
        bucket[p] = src[e];
    }
}

// ================================================================ fused gather + GEMM
// One wave per node (lane = channel). acc = (1+eps)*h[i] + sum_{j->i} h[j],
// then out[i][lane] = relu( sum_k acc_row[k] * W[lane][k] ).
__global__ __launch_bounds__(256) void fused_gin_kernel(
    const float* __restrict__ h, const int* __restrict__ off,
    const int* __restrict__ bucket, const float* __restrict__ W,
    const float* __restrict__ eps, float* __restrict__ out, int n)
{
    __shared__ float Wt[64][64];      // Wt[k][d] = W[d][k]
    __shared__ float rowbuf[4][64];   // per-wave agg row
    int tid = threadIdx.x;
    for (int i = tid; i < 4096; i += 256) Wt[i & 63][i >> 6] = W[i];
    __syncthreads();
    float s = 1.0f + eps[0];
    int lane = tid & 63;
    int w = tid >> 6;
    int wavesTotal = gridDim.x * 4;
    for (int i = blockIdx.x * 4 + w; i < n; i += wavesTotal) {
        float acc = s * h[(size_t)i * 64 + lane];
        int beg = off[i], end = off[i + 1];
        for (int j = beg; j < end; ++j) {
            int sid = bucket[j];                // uniform across wave
            acc += h[(size_t)sid * 64 + lane];  // coalesced 256B row
        }
        rowbuf[w][lane] = acc;
        __builtin_amdgcn_wave_barrier();
        float o = 0.f;
#pragma unroll
        for (int k = 0; k < 64; ++k) o += rowbuf[w][k] * Wt[k][lane];
        out[(size_t)i * 64 + lane] = fmaxf(o, 0.f);
        __builtin_amdgcn_wave_barrier();
    }
}

// Final: out[i] = ( relu(gin2_row @ W1^T) + h1[i] @ Wm^T ) / 2
__global__ __launch_bounds__(256) void fused_final_csr_kernel(
    const float* __restrict__ h1, const int* __restrict__ off,
    const int* __restrict__ bucket, const float* __restrict__ W1,
    const float* __restrict__ Wm, const float* __restrict__ eps,
    float* __restrict__ out, int n)
{
    __shared__ float W1t[64][64];
    __shared__ float Wmt[64][64];
    __shared__ float rowbuf[4][64];
    __shared__ float selfbuf[4][64];
    int tid = threadIdx.x;
    for (int i = tid; i < 4096; i += 256) {
        W1t[i & 63][i >> 6] = W1[i];
        Wmt[i & 63][i >> 6] = Wm[i];
    }
    __syncthreads();
    float s = 1.0f + eps[0];
    int lane = tid & 63;
    int w = tid >> 6;
    int wavesTotal = gridDim.x * 4;
    for (int i = blockIdx.x * 4 + w; i < n; i += wavesTotal) {
        float hv = h1[(size_t)i * 64 + lane];
        float acc = s * hv;
        int beg = off[i], end = off[i + 1];
        for (int j = beg; j < end; ++j) {
            int sid = bucket[j];
            acc += h1[(size_t)sid * 64 + lane];
        }
        rowbuf[w][lane] = acc;
        selfbuf[w][lane] = hv;
        __builtin_amdgcn_wave_barrier();
        float o1 = 0.f, o2 = 0.f;
#pragma unroll
        for (int k = 0; k < 64; ++k) {
            o1 += rowbuf[w][k] * W1t[k][lane];
            o2 += selfbuf[w][k] * Wmt[k][lane];
        }
        out[(size_t)i * 64 + lane] = (fmaxf(o1, 0.f) + o2) * 0.5f;
        __builtin_amdgcn_wave_barrier();
    }
}

// ================================================================ R1 fallback (atomic scatter)
__global__ __launch_bounds__(256) void init_scale_kernel(
    const float* __restrict__ h, const float* __restrict__ eps,
    float* __restrict__ agg, int total4)
{
    float s = 1.0f + eps[0];
    int i = blockIdx.x * blockDim.x + threadIdx.x;
    int stride = gridDim.x * blockDim.x;
    const float4* h4 = (const float4*)h;
    float4* a4 = (float4*)agg;
    for (; i < total4; i += stride) {
        float4 v = h4[i];
        v.x *= s; v.y *= s; v.z *= s; v.w *= s;
        a4[i] = v;
    }
}

__global__ __launch_bounds__(256) void scatter_kernel(
    const float* __restrict__ h, const int* __restrict__ src,
    const int* __restrict__ dst, float* __restrict__ agg, int E)
{
    int lane = threadIdx.x & 63;
    int e = blockIdx.x * 4 + (threadIdx.x >> 6);
    if (e >= E) return;
    int s = src[e];
    int d = dst[e];
    float v = h[(size_t)s * 64 + lane];
    atomicAdd(&agg[(size_t)d * 64 + lane], v);
}

__global__ __launch_bounds__(256) void gemm_relu_kernel(
    const float* __restrict__ A, const float* __restrict__ W,
    float* __restrict__ out, int n)
{
    __shared__ float Wt[64][64];
    __shared__ float As[16][68];
    int tid = threadIdx.x;
    for (int i = tid; i < 4096; i += 256) Wt[i & 63][i >> 6] = W[i];
    int row0 = blockIdx.x * 16;
    {
        int r = tid >> 4;
        int c = (tid & 15) * 4;
        if (row0 + r < n) {
            float4 v = *(const float4*)&A[(size_t)(row0 + r) * 64 + c];
            As[r][c] = v.x; As[r][c + 1] = v.y; As[r][c + 2] = v.z; As[r][c + 3] = v.w;
        }
    }
    __syncthreads();
    int ty = tid >> 4, tx = tid & 15;
    if (row0 + ty >= n) return;
    float4 acc = make_float4(0.f, 0.f, 0.f, 0.f);
#pragma unroll
    for (int k = 0; k < 64; ++k) {
        float a = As[ty][k];
        float4 w = *(const float4*)&Wt[k][tx * 4];
        acc.x += a * w.x; acc.y += a * w.y; acc.z += a * w.z; acc.w += a * w.w;
    }
    acc.x = fmaxf(acc.x, 0.f); acc.y = fmaxf(acc.y, 0.f);
    acc.z = fmaxf(acc.z, 0.f); acc.w = fmaxf(acc.w, 0.f);
    *(float4*)&out[(size_t)(row0 + ty) * 64 + tx * 4] = acc;
}

__global__ __launch_bounds__(256) void final_kernel(
    const float* __restrict__ Agg, const float* __restrict__ H1,
    const float* __restrict__ W1, const float* __restrict__ Wm,
    float* __restrict__ out, int n)
{
    __shared__ float W1t[64][64];
    __shared__ float Wmt[64][64];
    __shared__ float As[16][68];
    __shared__ float Hs[16][68];
    int tid = threadIdx.x;
    for (int i = tid; i < 4096; i += 256) {
        W1t[i & 63][i >> 6] = W1[i];
        Wmt[i & 63][i >> 6] = Wm[i];
    }
    int row0 = blockIdx.x * 16;
    {
        int r = tid >> 4;
        int c = (tid & 15) * 4;
        if (row0 + r < n) {
            float4 v = *(const float4*)&Agg[(size_t)(row0 + r) * 64 + c];
            As[r][c] = v.x; As[r][c + 1] = v.y; As[r][c + 2] = v.z; As[r][c + 3] = v.w;
            float4 u = *(const float4*)&H1[(size_t)(row0 + r) * 64 + c];
            Hs[r][c] = u.x; Hs[r][c + 1] = u.y; Hs[r][c + 2] = u.z; Hs[r][c + 3] = u.w;
        }
    }
    __syncthreads();
    int ty = tid >> 4, tx = tid & 15;
    if (row0 + ty >= n) return;
    float4 acc1 = make_float4(0.f, 0.f, 0.f, 0.f);
    float4 acc2 = make_float4(0.f, 0.f, 0.f, 0.f);
#pragma unroll
    for (int k = 0; k < 64; ++k) {
        float a = As[ty][k];
        float hv = Hs[ty][k];
        float4 w1 = *(const float4*)&W1t[k][tx * 4];
        float4 wm = *(const float4*)&Wmt[k][tx * 4];
        acc1.x += a * w1.x; acc1.y += a * w1.y; acc1.z += a * w1.z; acc1.w += a * w1.w;
        acc2.x += hv * wm.x; acc2.y += hv * wm.y; acc2.z += hv * wm.z; acc2.w += hv * wm.w;
    }
    float4 r;
    r.x = (fmaxf(acc1.x, 0.f) + acc2.x) * 0.5f;
    r.y = (fmaxf(acc1.y, 0.f) + acc2.y) * 0.5f;
    r.z = (fmaxf(acc1.z, 0.f) + acc2.z) * 0.5f;
    r.w = (fmaxf(acc1.w, 0.f) + acc2.w) * 0.5f;
    *(float4*)&out[(size_t)(row0 + ty) * 64 + tx * 4] = r;
}

// ================================================================ launch
extern "C" void kernel_launch(void* const* d_in, const int* in_sizes, int n_in,
                              void* d_out, int out_size, void* d_ws, size_t ws_size,
                              hipStream_t stream)
{
    const float* x    = (const float*)d_in[0];
    const int*   ei   = (const int*)d_in[1];
    const float* W0   = (const float*)d_in[2];
    const float* eps0 = (const float*)d_in[3];
    const float* W1   = (const float*)d_in[4];
    const float* eps1 = (const float*)d_in[5];
    const float* Wm   = (const float*)d_in[6];
    float* out = (float*)d_out;

    int n = in_sizes[0] / 64;   // 100000
    int E = in_sizes[1] / 2;    // 1600000
    const int* src = ei;
    const int* dst = ei + E;

    // ws layout for CSR path (all regions 1 KiB aligned)
    auto align1k = [](size_t v) { return (v + 1023) & ~(size_t)1023; };
    size_t h1_off     = 0;
    size_t off_off    = align1k(h1_off + (size_t)n * 64 * 4);
    size_t deg_off    = align1k(off_off + (size_t)(n + 1) * 4);
    size_t cursor_off = align1k(deg_off + (size_t)n * 4);
    size_t bsum_off   = align1k(cursor_off + (size_t)n * 4);
    size_t bucket_off = align1k(bsum_off + 256 * 4);
    size_t need       = bucket_off + (size_t)E * 4;

    if (ws_size >= need) {
        float* h1    = (float*)((char*)d_ws + h1_off);
        int* off     = (int*)((char*)d_ws + off_off);
        int* deg     = (int*)((char*)d_ws + deg_off);
        int* cursor  = (int*)((char*)d_ws + cursor_off);
        int* bsum    = (int*)((char*)d_ws + bsum_off);
        int* bucket  = (int*)((char*)d_ws + bucket_off);

        int nb = (n + 1023) / 1024;          // 98 (<=256 required)
        int eBlocks = (E + 255) / 256;       // 6250

        // CSR build (once, reused by both layers)
        zero_int_kernel<<<256, 256, 0, stream>>>(deg, n);
        hist_kernel<<<eBlocks, 256, 0, stream>>>(dst, deg, E);
        scanA_kernel<<<nb, 256, 0, stream>>>(deg, off, bsum, n);
        scanB_kernel<<<1, 256, 0, stream>>>(bsum, nb);
        scanC_kernel<<<nb, 256, 0, stream>>>(off, cursor, bsum, n, E);
        fill_kernel<<<eBlocks, 256, 0, stream>>>(src, dst, cursor, bucket, E);

        // Layer 1 fused gather+GEMM+relu -> h1 (ws)
        fused_gin_kernel<<<2048, 256, 0, stream>>>(x, off, bucket, W0, eps0, h1, n);
        // Layer 2 + merge fused -> out
        fused_final_csr_kernel<<<2048, 256, 0, stream>>>(h1, off, bucket, W1, Wm, eps1, out, n);
    } else {
        // R1 fallback: atomic scatter
        float* agg = (float*)d_ws;
        float* h1  = out;
        int total4 = n * 16;
        int scatterBlocks = (E + 3) / 4;
        int gemmBlocks = (n + 15) / 16;

        init_scale_kernel<<<2048, 256, 0, stream>>>(x, eps0, agg, total4);
        scatter_kernel<<<scatterBlocks, 256, 0, stream>>>(x, src, dst, agg, E);
        gemm_relu_kernel<<<gemmBlocks, 256, 0, stream>>>(agg, W0, h1, n);
        init_scale_kernel<<<2048, 256, 0, stream>>>(h1, eps1, agg, total4);
        scatter_kernel<<<scatterBlocks, 256, 0, stream>>>(h1, src, dst, agg, E);
        final_kernel<<<gemmBlocks, 256, 0, stream>>>(agg, h1, W1, Wm, out, n);
    }
}